// Round 7
// baseline (190.737 us; speedup 1.0000x reference)
//
#include <hip/hip_runtime.h>
#include <hip/hip_bf16.h>

// SelectiveDense: out[b,g,u] = relu(sum_k x[b, idx[g,k]] * kern[g,k,u] + bias[u])
// B=8192 D=4096 G=256 K=32 U=64. f32 in/out, bf16 MFMA compute.
// R6: vmcnt de-serialization — double-banked idx/kb prefetch issued BEFORE each
//     store burst (stores stay newest in the in-order VMEM queue -> no waitcnt
//     ever drains them). Grid 256 (1 block/CU), 2 b-tiles/block, XCD-chunked
//     swizzle (contiguous 64MB out slab per XCD). QG=4, 8 q-steps.

#define B_ 8192
#define D_ 4096
#define G_ 256
#define K_ 32
#define U_ 64
#define QG 4

typedef short v8s __attribute__((ext_vector_type(8)));     // 8 bf16 (4 VGPRs) MFMA A/B frag
typedef float f32x4 __attribute__((ext_vector_type(4)));   // MFMA C/D frag

__device__ __forceinline__ unsigned short f2bf(float f) {
    unsigned int u = __float_as_uint(f);
    u = (u + 0x7FFFu + ((u >> 16) & 1u)) >> 16;   // round-to-nearest-even
    return (unsigned short)u;
}

// Pre-pass: kernels f32 [G][K][U] -> bf16 frag layout [G][4 tiles][64 lanes][8]
// MFMA B operand for tile t: lane l holds B[k=(l>>4)*8+j][col=l&15], col -> u=4*col+t.
__global__ void prep_kb(const float* __restrict__ kern, unsigned short* __restrict__ kb) {
    int tid = blockIdx.x * blockDim.x + threadIdx.x;   // over G*K*U
    if (tid >= G_ * K_ * U_) return;
    int u = tid & (U_ - 1);
    int k = (tid >> 6) & (K_ - 1);
    int g = tid >> 11;
    int t = u & 3;                        // u-within-quad -> tile index
    int col = u >> 2;                     // quad index -> MFMA column
    int lane = ((k >> 3) << 4) | col;
    int j = k & 7;
    kb[((((g << 2) + t) << 6 | lane) << 3) | j] = f2bf(kern[tid]);
}

#define XS 4100   // LDS row stride (ushorts): bank shift 2/row -> gather ~conflict-free

#define LOADS(BANK, G0)                                                   \
    _Pragma("unroll")                                                     \
    for (int j = 0; j < QG; ++j) {                                        \
        const int4* ip = (const int4*)(idx + (((G0) + j) << 5) + kk0);    \
        pia[BANK][j] = ip[0]; pib[BANK][j] = ip[1];                       \
        const v8s* kg = kbv + (((G0) + j) << 8) + lane;                   \
        pk[BANK][j][0] = kg[0];   pk[BANK][j][1] = kg[64];                \
        pk[BANK][j][2] = kg[128]; pk[BANK][j][3] = kg[192];               \
    }

#define STEP(CB, NB, Q)                                                   \
    {                                                                     \
        const int g0 = ((Q) << 5) + (w << 2);                             \
        /* prefetch next step's idx+kb BEFORE this step's stores */       \
        LOADS(NB, (((((Q) + 1) & 7) << 5) + (w << 2)));                   \
        f32x4 acc[QG][4];                                                 \
        _Pragma("unroll")                                                 \
        for (int j = 0; j < QG; ++j) {                                    \
            union { unsigned short u[8]; v8s v; } A;                      \
            A.u[0] = lx[rowb + pia[CB][j].x];                             \
            A.u[1] = lx[rowb + pia[CB][j].y];                             \
            A.u[2] = lx[rowb + pia[CB][j].z];                             \
            A.u[3] = lx[rowb + pia[CB][j].w];                             \
            A.u[4] = lx[rowb + pib[CB][j].x];                             \
            A.u[5] = lx[rowb + pib[CB][j].y];                             \
            A.u[6] = lx[rowb + pib[CB][j].z];                             \
            A.u[7] = lx[rowb + pib[CB][j].w];                             \
            f32x4 z = {0.f, 0.f, 0.f, 0.f};                               \
            acc[j][0] = __builtin_amdgcn_mfma_f32_16x16x32_bf16(A.v, pk[CB][j][0], z, 0, 0, 0); \
            acc[j][1] = __builtin_amdgcn_mfma_f32_16x16x32_bf16(A.v, pk[CB][j][1], z, 0, 0, 0); \
            acc[j][2] = __builtin_amdgcn_mfma_f32_16x16x32_bf16(A.v, pk[CB][j][2], z, 0, 0, 0); \
            acc[j][3] = __builtin_amdgcn_mfma_f32_16x16x32_bf16(A.v, pk[CB][j][3], z, 0, 0, 0); \
        }                                                                 \
        _Pragma("unroll")                                                 \
        for (int r = 0; r < 4; ++r) {                                     \
            float* obr = out + (size_t)(b0 + (grp << 2) + r) * (G_ * U_)  \
                             + (g0 << 6) + (l15 << 2);                    \
            _Pragma("unroll")                                             \
            for (int j = 0; j < QG; ++j) {                                \
                float4 v;                                                 \
                v.x = acc[j][0][r] + bias_v.x;                            \
                v.y = acc[j][1][r] + bias_v.y;                            \
                v.z = acc[j][2][r] + bias_v.z;                            \
                v.w = acc[j][3][r] + bias_v.w;                            \
                v.x = v.x > 0.f ? v.x : 0.f;                              \
                v.y = v.y > 0.f ? v.y : 0.f;                              \
                v.z = v.z > 0.f ? v.z : 0.f;                              \
                v.w = v.w > 0.f ? v.w : 0.f;                              \
                *(float4*)(obr + (j << 6)) = v;                           \
            }                                                             \
        }                                                                 \
        __builtin_amdgcn_s_barrier();                                     \
    }

__global__ void __launch_bounds__(512) sdense(
        const float* __restrict__ x, const unsigned short* __restrict__ kb,
        const float* __restrict__ bias, const int* __restrict__ idx,
        float* __restrict__ out) {
    extern __shared__ unsigned short lx[];   // [16][XS] bf16 x rows
    const int tid = threadIdx.x;
    const int lane = tid & 63;
    const int w = tid >> 6;               // wave 0..7
    // XCD-chunked swizzle: hw assigns blockIdx round-robin to XCDs; remap so
    // XCD k owns contiguous tiles [32k, 32k+32) -> contiguous 64MB out slab.
    const int tile = ((blockIdx.x & 7) << 5) | (blockIdx.x >> 3);

    const int grp = lane >> 4;            // 0..3
    const int l15 = lane & 15;
    const int rowb = l15 * XS;            // A-operand: lane gathers x row b=l15
    const int kk0 = grp << 3;
    const float4 bias_v = *(const float4*)(bias + (l15 << 2));  // u = 4*l15 + 0..3
    const v8s* kbv = (const v8s*)kb;

    int4 pia[2][QG], pib[2][QG];          // double-banked pending idx
    v8s pk[2][QG][4];                     // double-banked pending kb frags

    for (int tt = 0; tt < 2; ++tt) {
        const int b0 = (((tile << 1) + tt) << 4);
        if (tt) __syncthreads();          // all tile-0 LDS reads done before restage

        // ---- stage 16 rows of x (f32 -> bf16): wave w -> rows 2w, 2w+1 ----
        {
            const int row = (w << 1) + (lane >> 5);
            const int l32 = lane & 31;
            const float* xr = x + (size_t)(b0 + row) * D_;
            unsigned short* lr = lx + row * XS;
            #pragma unroll
            for (int i = 0; i < 16; ++i) {
                int col = (i << 8) + (l32 << 3);       // 8 floats / lane / iter
                float4 v0 = *(const float4*)(xr + col);
                float4 v1 = *(const float4*)(xr + col + 4);
                union { unsigned short u[8]; v8s v; } st;
                st.u[0] = f2bf(v0.x); st.u[1] = f2bf(v0.y);
                st.u[2] = f2bf(v0.z); st.u[3] = f2bf(v0.w);
                st.u[4] = f2bf(v1.x); st.u[5] = f2bf(v1.y);
                st.u[6] = f2bf(v1.z); st.u[7] = f2bf(v1.w);
                *(v8s*)(lr + col) = st.v;              // 16B ds_write
            }
        }
        __syncthreads();

        // ---- pipelined q-loop: 8 steps x 32-g windows, QG=4 per wave ----
        LOADS(0, (w << 2));               // prologue: q=0 into bank 0
        for (int q2 = 0; q2 < 8; q2 += 2) {
            STEP(0, 1, q2);
            STEP(1, 0, q2 + 1);
        }
    }
}

extern "C" void kernel_launch(void* const* d_in, const int* in_sizes, int n_in,
                              void* d_out, int out_size, void* d_ws, size_t ws_size,
                              hipStream_t stream) {
    const float* x    = (const float*)d_in[0];
    const float* kern = (const float*)d_in[1];
    const float* bias = (const float*)d_in[2];
    const int*   idx  = (const int*)d_in[3];
    float* out = (float*)d_out;
    unsigned short* kb = (unsigned short*)d_ws;   // 1 MiB bf16 kernel frags

    prep_kb<<<(G_ * K_ * U_ + 255) / 256, 256, 0, stream>>>(kern, kb);
    sdense<<<B_ / 32, 512, 16 * XS * sizeof(unsigned short), stream>>>(x, kb, bias, idx, out);
}

// Round 8
// 169.211 us; speedup vs baseline: 1.1272x; 1.1272x over previous
//
#include <hip/hip_runtime.h>
#include <hip/hip_bf16.h>

// SelectiveDense: out[b,g,u] = relu(sum_k x[b, idx[g,k]] * kern[g,k,u] + bias[u])
// B=8192 D=4096 G=256 K=32 U=64. f32 in/out, bf16 MFMA compute.
// R7 = R5 minus the q-loop lockstep barrier (single change).
//     Theory: vmcnt retires in order, so each super-iter's first load-wait
//     drains the previous 32-store burst; with the barrier, all 8 waves idle
//     together. Free-running waves overlap one wave's drain with others'
//     gather/MFMA work. 2KB-per-row bursts keep per-burst page locality.

#define B_ 8192
#define D_ 4096
#define G_ 256
#define K_ 32
#define U_ 64
#define QG 8

typedef short v8s __attribute__((ext_vector_type(8)));     // 8 bf16 (4 VGPRs) MFMA A/B frag
typedef float f32x4 __attribute__((ext_vector_type(4)));   // MFMA C/D frag

__device__ __forceinline__ unsigned short f2bf(float f) {
    unsigned int u = __float_as_uint(f);
    u = (u + 0x7FFFu + ((u >> 16) & 1u)) >> 16;   // round-to-nearest-even
    return (unsigned short)u;
}

// Pre-pass: kernels f32 [G][K][U] -> bf16 frag layout [G][4 tiles][64 lanes][8]
// MFMA B operand for tile t: lane l holds B[k=(l>>4)*8+j][col=l&15], col -> u=4*col+t.
__global__ void prep_kb(const float* __restrict__ kern, unsigned short* __restrict__ kb) {
    int tid = blockIdx.x * blockDim.x + threadIdx.x;   // over G*K*U
    if (tid >= G_ * K_ * U_) return;
    int u = tid & (U_ - 1);
    int k = (tid >> 6) & (K_ - 1);
    int g = tid >> 11;
    int t = u & 3;                        // u-within-quad -> tile index
    int col = u >> 2;                     // quad index -> MFMA column
    int lane = ((k >> 3) << 4) | col;
    int j = k & 7;
    kb[((((g << 2) + t) << 6 | lane) << 3) | j] = f2bf(kern[tid]);
}

#define XS 4100   // LDS row stride (ushorts): bank shift 2/row -> gather ~conflict-free

__global__ void __launch_bounds__(512) sdense(
        const float* __restrict__ x, const unsigned short* __restrict__ kb,
        const float* __restrict__ bias, const int* __restrict__ idx,
        float* __restrict__ out) {
    extern __shared__ unsigned short lx[];   // [16][XS] bf16 x rows
    const int tid = threadIdx.x;
    const int b0 = blockIdx.x << 4;
    const int lane = tid & 63;
    const int w = tid >> 6;               // wave 0..7

    // ---- stage 16 rows of x (f32 -> bf16): wave w -> rows 2w, 2w+1 ----
    {
        const int row = (w << 1) + (lane >> 5);
        const int l32 = lane & 31;
        const float* xr = x + (size_t)(b0 + row) * D_;
        unsigned short* lr = lx + row * XS;
        #pragma unroll
        for (int i = 0; i < 16; ++i) {
            int col = (i << 8) + (l32 << 3);       // 8 floats / lane / iter
            float4 v0 = *(const float4*)(xr + col);
            float4 v1 = *(const float4*)(xr + col + 4);
            union { unsigned short u[8]; v8s v; } st;
            st.u[0] = f2bf(v0.x); st.u[1] = f2bf(v0.y);
            st.u[2] = f2bf(v0.z); st.u[3] = f2bf(v0.w);
            st.u[4] = f2bf(v1.x); st.u[5] = f2bf(v1.y);
            st.u[6] = f2bf(v1.z); st.u[7] = f2bf(v1.w);
            *(v8s*)(lr + col) = st.v;              // 16B ds_write
        }
    }
    __syncthreads();

    // ---- super-iter: wave w covers g in [64q+8w, 64q+8w+8); free-running ----
    const int grp = lane >> 4;            // 0..3
    const int l15 = lane & 15;
    const int rowb = l15 * XS;            // A-operand: lane gathers x row b=l15
    const int kk0 = grp << 3;

    const float4 bias_v = *(const float4*)(bias + (l15 << 2));  // u = 4*l15 + 0..3

    const v8s* kbv = (const v8s*)kb;

    for (int q = 0; q < 4; ++q) {
        const int g0 = (q << 6) + (w << 3);   // 64q + 8w

        f32x4 acc[QG][4];
        #pragma unroll
        for (int j = 0; j < QG; ++j) {
            const int g = g0 + j;
            const int4* ip = (const int4*)(idx + (g << 5) + kk0);
            int4 ia = ip[0], ib = ip[1];
            const v8s* kg = kbv + (g << 8) + lane;
            v8s k0 = kg[0], k1 = kg[64], k2 = kg[128], k3 = kg[192];

            union { unsigned short u[8]; v8s v; } A;  // A[m=b=l15][k=grp*8+jj]
            A.u[0] = lx[rowb + ia.x]; A.u[1] = lx[rowb + ia.y];
            A.u[2] = lx[rowb + ia.z]; A.u[3] = lx[rowb + ia.w];
            A.u[4] = lx[rowb + ib.x]; A.u[5] = lx[rowb + ib.y];
            A.u[6] = lx[rowb + ib.z]; A.u[7] = lx[rowb + ib.w];

            f32x4 z = {0.f, 0.f, 0.f, 0.f};
            acc[j][0] = __builtin_amdgcn_mfma_f32_16x16x32_bf16(A.v, k0, z, 0, 0, 0);
            acc[j][1] = __builtin_amdgcn_mfma_f32_16x16x32_bf16(A.v, k1, z, 0, 0, 0);
            acc[j][2] = __builtin_amdgcn_mfma_f32_16x16x32_bf16(A.v, k2, z, 0, 0, 0);
            acc[j][3] = __builtin_amdgcn_mfma_f32_16x16x32_bf16(A.v, k3, z, 0, 0, 0);
        }

        // store phase: r-outer; per row, 8 sequential dwordx4 instrs = 2KB contiguous
        #pragma unroll
        for (int r = 0; r < 4; ++r) {
            float* obr = out + (size_t)(b0 + (grp << 2) + r) * (G_ * U_)
                             + (g0 << 6) + (l15 << 2);
            #pragma unroll
            for (int j = 0; j < QG; ++j) {
                float4 v;
                v.x = acc[j][0][r] + bias_v.x;
                v.y = acc[j][1][r] + bias_v.y;
                v.z = acc[j][2][r] + bias_v.z;
                v.w = acc[j][3][r] + bias_v.w;
                v.x = v.x > 0.f ? v.x : 0.f;
                v.y = v.y > 0.f ? v.y : 0.f;
                v.z = v.z > 0.f ? v.z : 0.f;
                v.w = v.w > 0.f ? v.w : 0.f;
                *(float4*)(obr + (j << 6)) = v;
            }
        }
        // no barrier: waves free-run so one wave's store-drain overlaps
        // other waves' gather/MFMA work on this CU.
    }
}

extern "C" void kernel_launch(void* const* d_in, const int* in_sizes, int n_in,
                              void* d_out, int out_size, void* d_ws, size_t ws_size,
                              hipStream_t stream) {
    const float* x    = (const float*)d_in[0];
    const float* kern = (const float*)d_in[1];
    const float* bias = (const float*)d_in[2];
    const int*   idx  = (const int*)d_in[3];
    float* out = (float*)d_out;
    unsigned short* kb = (unsigned short*)d_ws;   // 1 MiB bf16 kernel frags

    prep_kb<<<(G_ * K_ * U_ + 255) / 256, 256, 0, stream>>>(kern, kb);
    sdense<<<B_ / 16, 512, 16 * XS * sizeof(unsigned short), stream>>>(x, kb, bias, idx, out);
}